// Round 13
// baseline (250.491 us; speedup 1.0000x reference)
//
#include <hip/hip_runtime.h>
#include <math.h>

typedef int intx4 __attribute__((ext_vector_type(4)));
typedef int intx8 __attribute__((ext_vector_type(8)));
typedef float floatx16 __attribute__((ext_vector_type(16)));

#define N_ROWS 8192
#define KDIM 1024

// E8M0 scale bytes: 123 -> 2^-4 per side (data pre-scaled by 2^4 each side)
#define SCALE_WORD 0x7B7B7B7B

// order-preserving float->int encoding for atomicMax
__device__ __forceinline__ int fenc(float f) {
  int i = __float_as_int(f);
  return i >= 0 ? i : (i ^ 0x7fffffff);
}
__device__ __forceinline__ float fdec(int e) {
  int b = e >= 0 ? e : (e ^ 0x7fffffff);
  return __int_as_float(b);
}

// async 16B global->LDS DMA (m97 pattern: per-lane global src, LDS dest must
// equal wave-uniform base + lane*16 -- ours does by construction).
__device__ __forceinline__ void gld_lds16(const void* g, void* l) {
  __builtin_amdgcn_global_load_lds(
      (const __attribute__((address_space(1))) unsigned int*)g,
      (__attribute__((address_space(3))) unsigned int*)l, 16, 0, 0);
}

// One WAVE per row (4 rows/block, no __syncthreads): computes 1/||x|| (fp32),
// writes row normalized*16 as e4m3 via HW cvt, inits the max slot.
__global__ __launch_bounds__(256) void normalize_kernel(
    const float* __restrict__ ex, const float* __restrict__ ey,
    unsigned char* __restrict__ exn, unsigned char* __restrict__ eyn,
    int* __restrict__ rowmax, int* __restrict__ colmax) {
  const int wave = threadIdx.x >> 6, lane = threadIdx.x & 63;
  const int gr = blockIdx.x * 4 + wave;  // 0..16383
  const float* x;
  unsigned char* out;
  int* mslot;
  int row;
  if (gr < N_ROWS) {
    x = ex; out = exn; mslot = rowmax; row = gr;
  } else {
    x = ey; out = eyn; mslot = colmax; row = gr - N_ROWS;
  }
  const float4* xr = (const float4*)(x + (size_t)row * KDIM);
  float4 v[4];
  float ss = 0.f;
#pragma unroll
  for (int j = 0; j < 4; ++j) {
    v[j] = xr[lane + j * 64];  // coalesced
    ss += v[j].x * v[j].x + v[j].y * v[j].y + v[j].z * v[j].z + v[j].w * v[j].w;
  }
#pragma unroll
  for (int off = 32; off > 0; off >>= 1) ss += __shfl_xor(ss, off, 64);
  const float rs = 16.0f * rsqrtf(fmaxf(ss, 1e-24f));  // 2^4 pre-scale
  int* op = (int*)(out + (size_t)row * KDIM);
#pragma unroll
  for (int j = 0; j < 4; ++j) {
    int w = __builtin_amdgcn_cvt_pk_fp8_f32(v[j].x * rs, v[j].y * rs, 0, false);
    w = __builtin_amdgcn_cvt_pk_fp8_f32(v[j].z * rs, v[j].w * rs, w, true);
    op[lane + j * 64] = w;
  }
  if (lane == 0) mslot[row] = (int)0x80000000;  // encoded -inf floor
}

// 256x256 tile GEMM (A @ B^T, row-major K-contiguous e4m3) using MX-scaled
// mfma_scale_f32_32x32x64_f8f6f4, fused with row/col max reduction.
//
// Round-24 change: r22 (best, 110 us) + 4-buffer LDS + barrier every 2
// tiles + union-half RD8 (validated r23). Ledger update from r23: 8-wave
// clean-but-137 FALSIFIED the LDS-amplification thesis -- at coarse
// 2-phase, TLP (4 waves/SIMD) outweighs LDS demand (m114 implicit
// overlap); m201's 2-waves/SIMD only works with the full fine-phase
// schedule we failed to transplant 3x (r18/r19/r21). So anchor on r22's
// 16-wave geometry and attack its measured gap instead: wall 4125 cy/tile
// vs LDS-busy ~2300 -> ~1800 cy convoy. All 16 waves are barrier-locked
// into the same phase: post-barrier LDS burst, then pipe idle. Fix:
// barrier HALF as often. With 4 buffers (tile t reads buf t%4, stages
// t+2 into (t+2)%4), the overwrite hazard needs a barrier only every 2
// tiles; wave skew up to ~1 tile develops inside each interval ->
// natural cross-wave pipelining, halved convoy events.
// Race audit: buf staged at tile t ((t+2)%4) was last read at tile t-2,
// BEFORE the previous barrier (all waves passed it) -> no overwrite race.
// DMA visibility: __syncthreads' vmcnt(0)+lgkmcnt(0) drain at each group
// tail retires BOTH groups staged in the interval; the youngest stage
// (issued just before the trailing COMPUTE) gets >= 1 compute phase
// (~2000+ cy) to land -- same margin as r22, proven. All buffer indices
// compile-time (4-tile loop body). Union RD8 (r23-validated): b128 loads
// land directly in intx8 halves, no shufflevector movs. Joint-revert to
// r22 if regression.
// LDS 128 KB static (m201 precedent). Tripwires: WRITE ~20 MB, VGPR
// ~64-arch, conflicts ~8.4M. Null -> convoy is not barrier-count-bound.
//
// LDS swizzle (verified r8): 64-B rows, 16-B chunk c of row r at slot
// c ^ ((r>>1)&3); staging pre-swizzles the per-lane global source chunk so
// the linear lane*16 dest lands swizzle-stored; fragment reads recover
// true chunk 2h+j -> operand bytes at (half,j,b) equal global
// k = k0+(2h+j)*16+b for BOTH A and B -> exact dot-product pairing.
// (Dest row = tid>>2 covers 0..255 at 1024 thr; f(row) = (tid>>3)&3;
// all read-row bases are multiples of 32 -> fsw invariant.)
__global__ __launch_bounds__(1024, 1) void gemm_max_kernel(
    const unsigned char* __restrict__ A, const unsigned char* __restrict__ B,
    int* __restrict__ rowmax, int* __restrict__ colmax) {
  constexpr int TM = 256, BK = 64, K = KDIM;
  constexpr int BUF = TM * BK;                          // 16 KB per buffer
  __shared__ __align__(16) unsigned char sA[4 * BUF];   // 64 KB
  __shared__ __align__(16) unsigned char sB[4 * BUF];   // 64 KB

  const int bm = blockIdx.x, bn = blockIdx.y;
  const int tid = threadIdx.x;  // 0..1023
  const int lane = tid & 63, wave = tid >> 6;
  const int wm = wave >> 2, wn = wave & 3;  // 4x4 waves of 64x64
  const int l32 = lane & 31, half = lane >> 5;
  const int fsw = (l32 >> 1) & 3;                 // f(row) = (row>>1)&3
  const int oLo = (((2 * half + 0) ^ fsw) << 4);  // swizzled slot offsets
  const int oHi = (((2 * half + 1) ^ fsw) << 4);

  const char* Ab = (const char*)(A + (size_t)bm * TM * K);
  const char* Bb = (const char*)(B + (size_t)bn * TM * K);

  typedef union {
    intx8 v8;
    intx4 v4[2];
  } frag8;

  floatx16 acc[2][2] = {};

  // Staging: 1024 lanes stage a 256x64 tile (16 KB) per array in ONE DMA.
  // Dest tid*16 -> row tid>>2 (0..255), slot tid&3.
  // Source chunk = (tid&3) ^ f(row) = (tid&3) ^ ((tid>>3)&3).
  const int src_c16 = (((tid & 3) ^ ((tid >> 3) & 3)) << 4);
  const char* gA = Ab + (size_t)(tid >> 2) * K + src_c16;
  const char* gB = Bb + (size_t)(tid >> 2) * K + src_c16;
  unsigned char* wA = sA + tid * 16;  // linear per-lane dest
  unsigned char* wB = sB + tid * 16;

#define STAGE(k0, buf)                              \
  do {                                              \
    gld_lds16(gA + (size_t)(k0), wA + (buf)*BUF);   \
    gld_lds16(gB + (size_t)(k0), wB + (buf)*BUF);   \
  } while (0)

  // union-half fragment read: two b128 loads land directly in the intx8
  // halves (no shufflevector movs; validated r23).
#define RD8(dst, p)                                   \
  do {                                                \
    (dst).v4[0] = *(const intx4*)((p) + oLo);         \
    (dst).v4[1] = *(const intx4*)((p) + oHi);         \
  } while (0)

#define COMPUTE(cur)                                                        \
  do {                                                                      \
    frag8 aF[2];                                                            \
    _Pragma("unroll") for (int mi = 0; mi < 2; ++mi) {                      \
      RD8(aF[mi], &sA[(cur)*BUF + (wm * 64 + mi * 32 + l32) * BK]);         \
    }                                                                       \
    _Pragma("unroll") for (int ni = 0; ni < 2; ++ni) {                      \
      frag8 bF;                                                             \
      RD8(bF, &sB[(cur)*BUF + (wn * 64 + ni * 32 + l32) * BK]);             \
      _Pragma("unroll") for (int mi = 0; mi < 2; ++mi)                      \
          acc[mi][ni] = __builtin_amdgcn_mfma_scale_f32_32x32x64_f8f6f4(    \
              aF[mi].v8, bF.v8, acc[mi][ni], 0, 0, 0, SCALE_WORD, 0,        \
              SCALE_WORD);                                                  \
    }                                                                       \
  } while (0)

  // Prologue: tiles 0,1 staged; drain -> resident.
  STAGE(0, 0);
  STAGE(BK, 1);
  __syncthreads();

  // Steady state: tile t reads buf t%4; stage t+2 into (t+2)%4 issues
  // just before the COMPUTE it hides under; ONE __syncthreads per 2
  // tiles (its vmcnt drain retires both staged groups). 4-tile body
  // keeps every buffer index compile-time.
#pragma unroll 1
  for (int g = 0; g < 3; ++g) {  // tiles 4g .. 4g+3
    STAGE((size_t)(4 * g + 2) * BK, 2);
    COMPUTE(0);
    STAGE((size_t)(4 * g + 3) * BK, 3);
    COMPUTE(1);
    __syncthreads();
    STAGE((size_t)(4 * g + 4) * BK, 0);
    COMPUTE(2);
    STAGE((size_t)(4 * g + 5) * BK, 1);
    COMPUTE(3);
    __syncthreads();
  }
  // tiles 12,13 (bufs 0,1): stage 14,15 -> bufs 2,3
  STAGE((size_t)14 * BK, 2);
  COMPUTE(0);
  STAGE((size_t)15 * BK, 3);
  COMPUTE(1);
  __syncthreads();
  // tiles 14,15 (bufs 2,3): no staging
  COMPUTE(2);
  COMPUTE(3);

#undef STAGE
#undef RD8
#undef COMPUTE

  // 32x32 C/D layout (m74/m101, dtype-independent):
  //   col = lane&31, row = (reg&3) + 8*(reg>>2) + 4*(lane>>5), reg in [0,16)
  // Row maxes: in-lane over ni, shuffle across 32 cols (masks 1..16 stay
  // within a half), l32==0 lanes write.
#pragma unroll
  for (int mi = 0; mi < 2; ++mi) {
#pragma unroll
    for (int reg = 0; reg < 16; ++reg) {
      float v = fmaxf(acc[mi][0][reg], acc[mi][1][reg]);
#pragma unroll
      for (int m = 1; m < 32; m <<= 1) v = fmaxf(v, __shfl_xor(v, m, 64));
      if (l32 == 0) {
        const int grow = bm * TM + wm * 64 + mi * 32 +
                         (reg & 3) + 8 * (reg >> 2) + 4 * half;
        atomicMax(&rowmax[grow], fenc(v));
      }
    }
  }
  // Col maxes: in-lane over mi,reg (32 vals), combine halves via xor 32.
#pragma unroll
  for (int ni = 0; ni < 2; ++ni) {
    float v = -3.402823466e38f;
#pragma unroll
    for (int mi = 0; mi < 2; ++mi)
#pragma unroll
      for (int reg = 0; reg < 16; ++reg) v = fmaxf(v, acc[mi][ni][reg]);
    v = fmaxf(v, __shfl_xor(v, 32, 64));
    if (half == 0) {
      const int gcol = bn * TM + wn * 64 + ni * 32 + l32;
      atomicMax(&colmax[gcol], fenc(v));
    }
  }
}

__global__ __launch_bounds__(1024) void finalize_kernel(
    const int* __restrict__ rowmax, const int* __restrict__ colmax,
    float* __restrict__ out) {
  const int tid = threadIdx.x;
  float s1 = 0.f, s2 = 0.f;
  for (int i = tid; i < N_ROWS; i += 1024) {
    s1 += 1.0f - fdec(rowmax[i]);
    s2 += 1.0f - fdec(colmax[i]);
  }
#pragma unroll
  for (int off = 32; off > 0; off >>= 1) {
    s1 += __shfl_down(s1, off, 64);
    s2 += __shfl_down(s2, off, 64);
  }
  __shared__ float r1[16], r2[16];
  if ((tid & 63) == 0) {
    r1[tid >> 6] = s1;
    r2[tid >> 6] = s2;
  }
  __syncthreads();
  if (tid == 0) {
    const double SIGMA = 0.3;
    const double H_CONST = 0.5 * log(2.0 * 3.14159265358979323846 * SIGMA * SIGMA) + 0.5;
    const float HS = (float)(H_CONST / SIGMA);
    float a1 = 0.f, a2 = 0.f;
#pragma unroll
    for (int w = 0; w < 16; ++w) {
      a1 += r1[w];
      a2 += r2[w];
    }
    out[0] = HS * a1;
    out[1] = HS * a2;
  }
}

extern "C" void kernel_launch(void* const* d_in, const int* in_sizes, int n_in,
                              void* d_out, int out_size, void* d_ws, size_t ws_size,
                              hipStream_t stream) {
  const float* ex = (const float*)d_in[0];
  const float* ey = (const float*)d_in[1];
  float* out = (float*)d_out;
  char* ws = (char*)d_ws;

  unsigned char* exn = (unsigned char*)ws;                                   // 8 MB
  unsigned char* eyn = (unsigned char*)(ws + (size_t)N_ROWS * KDIM);         // 8 MB
  int* rowmax = (int*)(ws + (size_t)N_ROWS * KDIM * 2);                      // 32 KB
  int* colmax = rowmax + N_ROWS;                                             // 32 KB

  normalize_kernel<<<2 * N_ROWS / 4, 256, 0, stream>>>(ex, ey, exn, eyn, rowmax, colmax);
  gemm_max_kernel<<<dim3(32, 32), 1024, 0, stream>>>(exn, eyn, rowmax, colmax);
  finalize_kernel<<<1, 1024, 0, stream>>>(rowmax, colmax, out);
}